// Round 7
// baseline (171.775 us; speedup 1.0000x reference)
//
#include <hip/hip_runtime.h>
#include <cstdint>
#include <cstddef>

#define LRALPHA 0.2f
#define LOG2E 1.44269504f

typedef _Float16 half8 __attribute__((ext_vector_type(8)));
typedef float f32x4 __attribute__((ext_vector_type(4)));
typedef int int4v __attribute__((ext_vector_type(4)));

// ---------------------------------------------------------------------------
// Kernel 1: Wh = h @ W (8192x512 @ 512x64), writes:
//   whTsw : f16, swizzled MFMA-B layout: [j/32][cp:4][cc:16][ks:4][e:8]
//           element = Wh[j32*32 + ks*8 + e][cp*16 + cc]   (1 MiB)
//   wh1s  : f32 [8192]  (Wh @ a[:64])  * log2e
//   wh2s  : f32 [8192]  (Wh @ a[64:])  * log2e
// (log2-domain: lrelu commutes with positive scaling, exp2 replaces exp)
// ---------------------------------------------------------------------------
__global__ __launch_bounds__(256) void k1_wh(
    const float* __restrict__ h, const float* __restrict__ W, const float* __restrict__ a,
    _Float16* __restrict__ whTsw, float* __restrict__ wh1s, float* __restrict__ wh2s)
{
  __shared__ __align__(16) float h_lds[32][34];   // [k][row]
  __shared__ __align__(16) float w_lds[32][64];   // [k][col]
  __shared__ __align__(16) _Float16 whT_l[64][32]; // [col][ilocal]

  const int t = threadIdx.x;
  const int tx = t & 15, ty = t >> 4;
  const int i0 = blockIdx.x * 32;

  const int hrow = t >> 3, hk4 = (t & 7) * 4;
  const int wk = t >> 3, wc = (t & 7) * 8;

  float acc00 = 0, acc01 = 0, acc02 = 0, acc03 = 0;
  float acc10 = 0, acc11 = 0, acc12 = 0, acc13 = 0;

  float4 hv  = *reinterpret_cast<const float4*>(&h[(size_t)(i0 + hrow) * 512 + hk4]);
  float4 wv0 = *reinterpret_cast<const float4*>(&W[(size_t)wk * 64 + wc]);
  float4 wv1 = *reinterpret_cast<const float4*>(&W[(size_t)wk * 64 + wc + 4]);

  for (int k0 = 0; k0 < 512; k0 += 32) {
    h_lds[hk4 + 0][hrow] = hv.x;
    h_lds[hk4 + 1][hrow] = hv.y;
    h_lds[hk4 + 2][hrow] = hv.z;
    h_lds[hk4 + 3][hrow] = hv.w;
    *reinterpret_cast<float4*>(&w_lds[wk][wc])     = wv0;
    *reinterpret_cast<float4*>(&w_lds[wk][wc + 4]) = wv1;
    __syncthreads();
    if (k0 + 32 < 512) {
      hv  = *reinterpret_cast<const float4*>(&h[(size_t)(i0 + hrow) * 512 + k0 + 32 + hk4]);
      wv0 = *reinterpret_cast<const float4*>(&W[(size_t)(k0 + 32 + wk) * 64 + wc]);
      wv1 = *reinterpret_cast<const float4*>(&W[(size_t)(k0 + 32 + wk) * 64 + wc + 4]);
    }
#pragma unroll
    for (int kk = 0; kk < 32; ++kk) {
      float2 av = *reinterpret_cast<const float2*>(&h_lds[kk][ty * 2]);
      float4 bv = *reinterpret_cast<const float4*>(&w_lds[kk][tx * 4]);
      acc00 += av.x * bv.x; acc01 += av.x * bv.y; acc02 += av.x * bv.z; acc03 += av.x * bv.w;
      acc10 += av.y * bv.x; acc11 += av.y * bv.y; acc12 += av.y * bv.z; acc13 += av.y * bv.w;
    }
    __syncthreads();
  }

  const float a10 = a[tx * 4 + 0], a11 = a[tx * 4 + 1], a12 = a[tx * 4 + 2], a13 = a[tx * 4 + 3];
  const float a20 = a[64 + tx * 4 + 0], a21 = a[64 + tx * 4 + 1], a22 = a[64 + tx * 4 + 2], a23 = a[64 + tx * 4 + 3];
  float s1_0 = acc00 * a10 + acc01 * a11 + acc02 * a12 + acc03 * a13;
  float s1_1 = acc10 * a10 + acc11 * a11 + acc12 * a12 + acc13 * a13;
  float s2_0 = acc00 * a20 + acc01 * a21 + acc02 * a22 + acc03 * a23;
  float s2_1 = acc10 * a20 + acc11 * a21 + acc12 * a22 + acc13 * a23;
#pragma unroll
  for (int m = 1; m < 16; m <<= 1) {
    s1_0 += __shfl_xor(s1_0, m); s1_1 += __shfl_xor(s1_1, m);
    s2_0 += __shfl_xor(s2_0, m); s2_1 += __shfl_xor(s2_1, m);
  }
  if (tx == 0) {
    wh1s[i0 + ty * 2 + 0] = s1_0 * LOG2E; wh1s[i0 + ty * 2 + 1] = s1_1 * LOG2E;
    wh2s[i0 + ty * 2 + 0] = s2_0 * LOG2E; wh2s[i0 + ty * 2 + 1] = s2_1 * LOG2E;
  }

  whT_l[tx * 4 + 0][ty * 2 + 0] = (_Float16)acc00;
  whT_l[tx * 4 + 1][ty * 2 + 0] = (_Float16)acc01;
  whT_l[tx * 4 + 2][ty * 2 + 0] = (_Float16)acc02;
  whT_l[tx * 4 + 3][ty * 2 + 0] = (_Float16)acc03;
  whT_l[tx * 4 + 0][ty * 2 + 1] = (_Float16)acc10;
  whT_l[tx * 4 + 1][ty * 2 + 1] = (_Float16)acc11;
  whT_l[tx * 4 + 2][ty * 2 + 1] = (_Float16)acc12;
  whT_l[tx * 4 + 3][ty * 2 + 1] = (_Float16)acc13;
  __syncthreads();
  {
    const int cp = t >> 6, cc = (t >> 2) & 15, ks = t & 3;
    half8 v = *reinterpret_cast<const half8*>(&whT_l[cp * 16 + cc][ks * 8]);
    *reinterpret_cast<half8*>(&whTsw[(size_t)(i0 >> 5) * 2048 + cp * 512 + (cc * 4 + ks) * 8]) = v;
  }
}

// ---------------------------------------------------------------------------
// Kernel 1b: Gs = max(wh2s)   (scaled domain; max commutes with pos. scale)
// ---------------------------------------------------------------------------
__global__ __launch_bounds__(256) void k1b_max(const float* __restrict__ wh2s,
                                               float* __restrict__ G)
{
  const int t = threadIdx.x;
  float m = -1e30f;
  for (int i = t; i < 8192; i += 256) m = fmaxf(m, wh2s[i]);
#pragma unroll
  for (int mask = 32; mask >= 1; mask >>= 1) m = fmaxf(m, __shfl_xor(m, mask));
  __shared__ float wm[4];
  if ((t & 63) == 0) wm[t >> 6] = m;
  __syncthreads();
  if (t == 0) G[0] = fmaxf(fmaxf(wm[0], wm[1]), fmaxf(wm[2], wm[3]));
}

// ---------------------------------------------------------------------------
// Kernel 2f (v7): fused score+PV with DENSE adj reads.
// 512 blocks x 512 thr (8 waves), 2 blocks/CU. Block = 16 rows, full j in 16
// chunks of 512. Score: wave w owns rows {2w, 2w+1}; per chunk each row is
// read as 64 lanes x 32B = 2KB CONTIGUOUS (one row per load-pair, sequential
// across chunks -> DRAM row-buffer friendly). p -> f16 -> XOR-swizzled LDS
// tile [16][512] (dbuf). PV: wave w = (kh=w>>2, cp=w&3): 8 jb x (ds_read A,
// dense 1KB B from whTsw, MFMA); B loads issued BEFORE adj prefetch so vmcnt
// waits never drain the adj stream; adj prefetched 2 chunks ahead.
// Denominator: f32 per-lane chain, wave-reduced at end. 1 barrier/chunk.
// ---------------------------------------------------------------------------
__global__ __launch_bounds__(512, 4) void k2f(
    const int* __restrict__ adj, const _Float16* __restrict__ whTsw,
    const float* __restrict__ wh1s, const float* __restrict__ wh2s,
    const float* __restrict__ Gp, float* __restrict__ out)
{
  __shared__ __align__(16) _Float16 Plds[2][16][512];  // 32 KB p dbuf
  __shared__ float Osm[2][4][16][16];                  // 8 KB split-K partials
  __shared__ float Dsh[16];

  const int t = threadIdx.x;
  const int lane = t & 63;
  const int w = t >> 6;
  const int i0 = blockIdx.x * 16;

  // ---- score role: rows 2w, 2w+1 ----
  const int rA = w * 2, rB = rA + 1;
  const float Gs = Gp[0];
  const float w1A = wh1s[i0 + rA], w1B = wh1s[i0 + rB];
  const float mxA = w1A + Gs, mxB = w1B + Gs;
  const float mhA = fmaxf(mxA, LRALPHA * mxA);   // >= all scaled scores (lrelu monotone)
  const float mhB = fmaxf(mxB, LRALPHA * mxB);

  const int* adjA = adj + (size_t)(i0 + rA) * 8192 + lane * 8;
  const int* adjB = adj + (size_t)(i0 + rB) * 8192 + lane * 8;
  const float* wp = wh2s + lane * 8;

  // ---- PV role ----
  const int c = lane & 15, ks = lane >> 4;
  const int cp = w & 3, kh = w >> 2;
  const int cxor = (c & 7) << 4;
  char* PldsB = reinterpret_cast<char*>(&Plds[0][0][0]);
  const _Float16* bbase = whTsw + (size_t)kh * 8 * 2048 + cp * 512 + c * 32 + ks * 8;

  float psA = 0.f, psB = 0.f;
  f32x4 acc = {0.f, 0.f, 0.f, 0.f};

  int4v s0Aa, s0Ab, s0Ba, s0Bb, s1Aa, s1Ab, s1Ba, s1Bb;
  float4 qa, qb;
  half8 b0, b1, b2, b3, b4, b5, b6, b7;

#define LOAD_ADJ(S, CH) do { \
    S##Aa = __builtin_nontemporal_load(reinterpret_cast<const int4v*>(adjA + (CH) * 512)); \
    S##Ab = __builtin_nontemporal_load(reinterpret_cast<const int4v*>(adjA + (CH) * 512 + 4)); \
    S##Ba = __builtin_nontemporal_load(reinterpret_cast<const int4v*>(adjB + (CH) * 512)); \
    S##Bb = __builtin_nontemporal_load(reinterpret_cast<const int4v*>(adjB + (CH) * 512 + 4)); \
  } while (0)

#define LOAD_WH(CH) do { \
    qa = *reinterpret_cast<const float4*>(wp + (CH) * 512); \
    qb = *reinterpret_cast<const float4*>(wp + (CH) * 512 + 4); \
  } while (0)

#define SC1(PS, PV, E, AV, QV, W1, MH) { \
    float x_ = (W1) + (QV); x_ = fmaxf(x_, LRALPHA * x_); \
    float p_ = ((AV) > 0) ? exp2f(x_ - (MH)) : 0.f; \
    (PS) += p_; (PV)[E] = (_Float16)p_; }

#define COMP_STORE(S, CH) do { \
    half8 pvA_, pvB_; \
    SC1(psA, pvA_, 0, S##Aa.x, qa.x, w1A, mhA) \
    SC1(psA, pvA_, 1, S##Aa.y, qa.y, w1A, mhA) \
    SC1(psA, pvA_, 2, S##Aa.z, qa.z, w1A, mhA) \
    SC1(psA, pvA_, 3, S##Aa.w, qa.w, w1A, mhA) \
    SC1(psA, pvA_, 4, S##Ab.x, qb.x, w1A, mhA) \
    SC1(psA, pvA_, 5, S##Ab.y, qb.y, w1A, mhA) \
    SC1(psA, pvA_, 6, S##Ab.z, qb.z, w1A, mhA) \
    SC1(psA, pvA_, 7, S##Ab.w, qb.w, w1A, mhA) \
    SC1(psB, pvB_, 0, S##Ba.x, qa.x, w1B, mhB) \
    SC1(psB, pvB_, 1, S##Ba.y, qa.y, w1B, mhB) \
    SC1(psB, pvB_, 2, S##Ba.z, qa.z, w1B, mhB) \
    SC1(psB, pvB_, 3, S##Ba.w, qa.w, w1B, mhB) \
    SC1(psB, pvB_, 4, S##Bb.x, qb.x, w1B, mhB) \
    SC1(psB, pvB_, 5, S##Bb.y, qb.y, w1B, mhB) \
    SC1(psB, pvB_, 6, S##Bb.z, qb.z, w1B, mhB) \
    SC1(psB, pvB_, 7, S##Bb.w, qb.w, w1B, mhB) \
    char* pb_ = PldsB + ((CH) & 1) * 16384; \
    *reinterpret_cast<half8*>(pb_ + rA * 1024 + ((lane * 16) ^ ((rA & 7) << 4))) = pvA_; \
    *reinterpret_cast<half8*>(pb_ + rB * 1024 + ((lane * 16) ^ ((rB & 7) << 4))) = pvB_; \
  } while (0)

#define PV_LOADB(CH) do { \
    const _Float16* bp_ = bbase + (size_t)(CH) * 32768; \
    b0 = *reinterpret_cast<const half8*>(bp_ + 0 * 2048); \
    b1 = *reinterpret_cast<const half8*>(bp_ + 1 * 2048); \
    b2 = *reinterpret_cast<const half8*>(bp_ + 2 * 2048); \
    b3 = *reinterpret_cast<const half8*>(bp_ + 3 * 2048); \
    b4 = *reinterpret_cast<const half8*>(bp_ + 4 * 2048); \
    b5 = *reinterpret_cast<const half8*>(bp_ + 5 * 2048); \
    b6 = *reinterpret_cast<const half8*>(bp_ + 6 * 2048); \
    b7 = *reinterpret_cast<const half8*>(bp_ + 7 * 2048); \
  } while (0)

#define PV_MFMA(CH) do { \
    const char* pr_ = PldsB + ((CH) & 1) * 16384 + c * 1024 + kh * 512; \
    half8 a_; \
    a_ = *reinterpret_cast<const half8*>(pr_ + ((0 * 64 + ks * 16) ^ cxor)); \
    acc = __builtin_amdgcn_mfma_f32_16x16x32_f16(a_, b0, acc, 0, 0, 0); \
    a_ = *reinterpret_cast<const half8*>(pr_ + ((1 * 64 + ks * 16) ^ cxor)); \
    acc = __builtin_amdgcn_mfma_f32_16x16x32_f16(a_, b1, acc, 0, 0, 0); \
    a_ = *reinterpret_cast<const half8*>(pr_ + ((2 * 64 + ks * 16) ^ cxor)); \
    acc = __builtin_amdgcn_mfma_f32_16x16x32_f16(a_, b2, acc, 0, 0, 0); \
    a_ = *reinterpret_cast<const half8*>(pr_ + ((3 * 64 + ks * 16) ^ cxor)); \
    acc = __builtin_amdgcn_mfma_f32_16x16x32_f16(a_, b3, acc, 0, 0, 0); \
    a_ = *reinterpret_cast<const half8*>(pr_ + ((4 * 64 + ks * 16) ^ cxor)); \
    acc = __builtin_amdgcn_mfma_f32_16x16x32_f16(a_, b4, acc, 0, 0, 0); \
    a_ = *reinterpret_cast<const half8*>(pr_ + ((5 * 64 + ks * 16) ^ cxor)); \
    acc = __builtin_amdgcn_mfma_f32_16x16x32_f16(a_, b5, acc, 0, 0, 0); \
    a_ = *reinterpret_cast<const half8*>(pr_ + ((6 * 64 + ks * 16) ^ cxor)); \
    acc = __builtin_amdgcn_mfma_f32_16x16x32_f16(a_, b6, acc, 0, 0, 0); \
    a_ = *reinterpret_cast<const half8*>(pr_ + ((7 * 64 + ks * 16) ^ cxor)); \
    acc = __builtin_amdgcn_mfma_f32_16x16x32_f16(a_, b7, acc, 0, 0, 0); \
  } while (0)

  // pr_ note: kh*512 bytes = jb base (kh*8 fragments x 64B); XOR only touches
  // bits 4-6 so adding j*64 (bit 6+) before XOR with (c&7)<<4 matches the
  // write-side swizzle exactly (write: byte lane*16 ^ ((r&7)<<4)).

#define BODY(CH, LD, CM) { \
    PV_LOADB(CH); \
    if ((CH) < 14) LOAD_ADJ(LD, (CH) + 2); \
    if ((CH) < 15) LOAD_WH((CH) + 1); \
    PV_MFMA(CH); \
    if ((CH) < 15) COMP_STORE(CM, (CH) + 1); \
    __syncthreads(); }

  // prologue: fill pipeline (adj 2 ahead, wh 1 ahead)
  LOAD_ADJ(s0, 0);
  LOAD_WH(0);
  LOAD_ADJ(s1, 1);
  COMP_STORE(s0, 0);
  __syncthreads();

  BODY(0,  s0, s1)  BODY(1,  s1, s0)
  BODY(2,  s0, s1)  BODY(3,  s1, s0)
  BODY(4,  s0, s1)  BODY(5,  s1, s0)
  BODY(6,  s0, s1)  BODY(7,  s1, s0)
  BODY(8,  s0, s1)  BODY(9,  s1, s0)
  BODY(10, s0, s1)  BODY(11, s1, s0)
  BODY(12, s0, s1)  BODY(13, s1, s0)
  BODY(14, s0, s1)  BODY(15, s1, s0)

#undef BODY
#undef PV_MFMA
#undef PV_LOADB
#undef COMP_STORE
#undef SC1
#undef LOAD_WH
#undef LOAD_ADJ

  // ---- epilogue: denom reduce, split-K combine, divide, ELU, store ----
#pragma unroll
  for (int m = 1; m < 64; m <<= 1) {
    psA += __shfl_xor(psA, m);
    psB += __shfl_xor(psB, m);
  }
  if (lane == 0) { Dsh[rA] = psA; Dsh[rB] = psB; }
#pragma unroll
  for (int q = 0; q < 4; ++q) Osm[kh][cp][ks * 4 + q][c] = acc[q];
  __syncthreads();

  {
    const int row = t >> 5;
    const int col = (t & 31) * 2;
    const int cg = col >> 4, cc = col & 15;
    const float inv = 1.0f / Dsh[row];
    float o0 = (Osm[0][cg][row][cc] + Osm[1][cg][row][cc]) * inv;
    float o1 = (Osm[0][cg][row][cc + 1] + Osm[1][cg][row][cc + 1]) * inv;
    o0 = o0 > 0.f ? o0 : __expf(o0) - 1.f;
    o1 = o1 > 0.f ? o1 : __expf(o1) - 1.f;
    float2 o = {o0, o1};
    *reinterpret_cast<float2*>(&out[(size_t)(i0 + row) * 64 + col]) = o;
  }
}

// ---------------------------------------------------------------------------
extern "C" void kernel_launch(void* const* d_in, const int* in_sizes, int n_in,
                              void* d_out, int out_size, void* d_ws, size_t ws_size,
                              hipStream_t stream) {
  const float* h   = (const float*)d_in[0];
  const int*   adj = (const int*)d_in[1];
  const float* W   = (const float*)d_in[2];
  const float* a   = (const float*)d_in[3];
  float* out = (float*)d_out;

  char* ws = (char*)d_ws;
  _Float16* whTsw = (_Float16*)ws;                         // [0, 1MB)
  float* wh1s = (float*)(ws + 0x100000);                   // 32 KB
  float* wh2s = (float*)(ws + 0x108000);                   // 32 KB
  float* G    = (float*)(ws + 0x110000);                   // 4 B

  k1_wh<<<dim3(256), dim3(256), 0, stream>>>(h, W, a, whTsw, wh1s, wh2s);
  k1b_max<<<dim3(1), dim3(256), 0, stream>>>(wh2s, G);
  k2f<<<dim3(512), dim3(512), 0, stream>>>(adj, whTsw, wh1s, wh2s, G, out);
}

// Round 8
// 160.563 us; speedup vs baseline: 1.0698x; 1.0698x over previous
//
#include <hip/hip_runtime.h>
#include <cstdint>
#include <cstddef>

#define LRALPHA 0.2f
#define LOG2E 1.44269504f

typedef _Float16 half8 __attribute__((ext_vector_type(8)));
typedef float f32x4 __attribute__((ext_vector_type(4)));
typedef int int4v __attribute__((ext_vector_type(4)));

// ---------------------------------------------------------------------------
// Kernel 1: Wh = h @ W (8192x512 @ 512x64), writes:
//   whTsw : f16, swizzled MFMA-B layout: [j/32][cp:4][cc:16][ks:4][e:8]
//           element = Wh[j32*32 + ks*8 + e][cp*16 + cc]   (1 MiB)
//   wh1s  : f32 [8192]  (Wh @ a[:64])  * log2e
//   wh2s  : f32 [8192]  (Wh @ a[64:])  * log2e
// ---------------------------------------------------------------------------
__global__ __launch_bounds__(256) void k1_wh(
    const float* __restrict__ h, const float* __restrict__ W, const float* __restrict__ a,
    _Float16* __restrict__ whTsw, float* __restrict__ wh1s, float* __restrict__ wh2s)
{
  __shared__ __align__(16) float h_lds[32][34];   // [k][row]
  __shared__ __align__(16) float w_lds[32][64];   // [k][col]
  __shared__ __align__(16) _Float16 whT_l[64][32]; // [col][ilocal]

  const int t = threadIdx.x;
  const int tx = t & 15, ty = t >> 4;
  const int i0 = blockIdx.x * 32;

  const int hrow = t >> 3, hk4 = (t & 7) * 4;
  const int wk = t >> 3, wc = (t & 7) * 8;

  float acc00 = 0, acc01 = 0, acc02 = 0, acc03 = 0;
  float acc10 = 0, acc11 = 0, acc12 = 0, acc13 = 0;

  float4 hv  = *reinterpret_cast<const float4*>(&h[(size_t)(i0 + hrow) * 512 + hk4]);
  float4 wv0 = *reinterpret_cast<const float4*>(&W[(size_t)wk * 64 + wc]);
  float4 wv1 = *reinterpret_cast<const float4*>(&W[(size_t)wk * 64 + wc + 4]);

  for (int k0 = 0; k0 < 512; k0 += 32) {
    h_lds[hk4 + 0][hrow] = hv.x;
    h_lds[hk4 + 1][hrow] = hv.y;
    h_lds[hk4 + 2][hrow] = hv.z;
    h_lds[hk4 + 3][hrow] = hv.w;
    *reinterpret_cast<float4*>(&w_lds[wk][wc])     = wv0;
    *reinterpret_cast<float4*>(&w_lds[wk][wc + 4]) = wv1;
    __syncthreads();
    if (k0 + 32 < 512) {
      hv  = *reinterpret_cast<const float4*>(&h[(size_t)(i0 + hrow) * 512 + k0 + 32 + hk4]);
      wv0 = *reinterpret_cast<const float4*>(&W[(size_t)(k0 + 32 + wk) * 64 + wc]);
      wv1 = *reinterpret_cast<const float4*>(&W[(size_t)(k0 + 32 + wk) * 64 + wc + 4]);
    }
#pragma unroll
    for (int kk = 0; kk < 32; ++kk) {
      float2 av = *reinterpret_cast<const float2*>(&h_lds[kk][ty * 2]);
      float4 bv = *reinterpret_cast<const float4*>(&w_lds[kk][tx * 4]);
      acc00 += av.x * bv.x; acc01 += av.x * bv.y; acc02 += av.x * bv.z; acc03 += av.x * bv.w;
      acc10 += av.y * bv.x; acc11 += av.y * bv.y; acc12 += av.y * bv.z; acc13 += av.y * bv.w;
    }
    __syncthreads();
  }

  const float a10 = a[tx * 4 + 0], a11 = a[tx * 4 + 1], a12 = a[tx * 4 + 2], a13 = a[tx * 4 + 3];
  const float a20 = a[64 + tx * 4 + 0], a21 = a[64 + tx * 4 + 1], a22 = a[64 + tx * 4 + 2], a23 = a[64 + tx * 4 + 3];
  float s1_0 = acc00 * a10 + acc01 * a11 + acc02 * a12 + acc03 * a13;
  float s1_1 = acc10 * a10 + acc11 * a11 + acc12 * a12 + acc13 * a13;
  float s2_0 = acc00 * a20 + acc01 * a21 + acc02 * a22 + acc03 * a23;
  float s2_1 = acc10 * a20 + acc11 * a21 + acc12 * a22 + acc13 * a23;
#pragma unroll
  for (int m = 1; m < 16; m <<= 1) {
    s1_0 += __shfl_xor(s1_0, m); s1_1 += __shfl_xor(s1_1, m);
    s2_0 += __shfl_xor(s2_0, m); s2_1 += __shfl_xor(s2_1, m);
  }
  if (tx == 0) {
    wh1s[i0 + ty * 2 + 0] = s1_0 * LOG2E; wh1s[i0 + ty * 2 + 1] = s1_1 * LOG2E;
    wh2s[i0 + ty * 2 + 0] = s2_0 * LOG2E; wh2s[i0 + ty * 2 + 1] = s2_1 * LOG2E;
  }

  whT_l[tx * 4 + 0][ty * 2 + 0] = (_Float16)acc00;
  whT_l[tx * 4 + 1][ty * 2 + 0] = (_Float16)acc01;
  whT_l[tx * 4 + 2][ty * 2 + 0] = (_Float16)acc02;
  whT_l[tx * 4 + 3][ty * 2 + 0] = (_Float16)acc03;
  whT_l[tx * 4 + 0][ty * 2 + 1] = (_Float16)acc10;
  whT_l[tx * 4 + 1][ty * 2 + 1] = (_Float16)acc11;
  whT_l[tx * 4 + 2][ty * 2 + 1] = (_Float16)acc12;
  whT_l[tx * 4 + 3][ty * 2 + 1] = (_Float16)acc13;
  __syncthreads();
  {
    const int cp = t >> 6, cc = (t >> 2) & 15, ks = t & 3;
    half8 v = *reinterpret_cast<const half8*>(&whT_l[cp * 16 + cc][ks * 8]);
    *reinterpret_cast<half8*>(&whTsw[(size_t)(i0 >> 5) * 2048 + cp * 512 + (cc * 4 + ks) * 8]) = v;
  }
}

// ---------------------------------------------------------------------------
// Kernel 1b: Gs = max(wh2s)
// ---------------------------------------------------------------------------
__global__ __launch_bounds__(256) void k1b_max(const float* __restrict__ wh2s,
                                               float* __restrict__ G)
{
  const int t = threadIdx.x;
  float m = -1e30f;
  for (int i = t; i < 8192; i += 256) m = fmaxf(m, wh2s[i]);
#pragma unroll
  for (int mask = 32; mask >= 1; mask >>= 1) m = fmaxf(m, __shfl_xor(m, mask));
  __shared__ float wm[4];
  if ((t & 63) == 0) wm[t >> 6] = m;
  __syncthreads();
  if (t == 0) G[0] = fmaxf(fmaxf(wm[0], wm[1]), fmaxf(wm[2], wm[3]));
}

// ---------------------------------------------------------------------------
// Kernel 2f (v8): fused score+PV with DENSE adj reads — spill-free edition.
// Same structure as v7 but: depth-1 adj prefetch (the compiler's vmcnt(0)
// drain before every s_barrier makes depth-2 useless anyway) and
// __launch_bounds__(512, 2) so the allocator has ~128 VGPRs (no scratch).
// Per chunk: B-frags (L2) issued FIRST, then adj (HBM) + wh, then MFMA on
// the previous chunk's LDS tile, then score+store for the next tile.
// ---------------------------------------------------------------------------
__global__ __launch_bounds__(512, 2) void k2f(
    const int* __restrict__ adj, const _Float16* __restrict__ whTsw,
    const float* __restrict__ wh1s, const float* __restrict__ wh2s,
    const float* __restrict__ Gp, float* __restrict__ out)
{
  __shared__ __align__(16) _Float16 Plds[2][16][512];  // 32 KB p dbuf
  __shared__ float Osm[2][4][16][16];                  // 8 KB split-K partials
  __shared__ float Dsh[16];

  const int t = threadIdx.x;
  const int lane = t & 63;
  const int w = t >> 6;
  const int i0 = blockIdx.x * 16;

  // ---- score role: rows 2w, 2w+1 ----
  const int rA = w * 2, rB = rA + 1;
  const float Gs = Gp[0];
  const float w1A = wh1s[i0 + rA], w1B = wh1s[i0 + rB];
  const float mxA = w1A + Gs, mxB = w1B + Gs;
  const float mhA = fmaxf(mxA, LRALPHA * mxA);   // >= all scaled scores (lrelu monotone)
  const float mhB = fmaxf(mxB, LRALPHA * mxB);

  const int* adjA = adj + (size_t)(i0 + rA) * 8192 + lane * 8;
  const int* adjB = adj + (size_t)(i0 + rB) * 8192 + lane * 8;
  const float* wp = wh2s + lane * 8;

  // ---- PV role ----
  const int c = lane & 15, ks = lane >> 4;
  const int cp = w & 3, kh = w >> 2;
  const int cxor = (c & 7) << 4;
  char* PldsB = reinterpret_cast<char*>(&Plds[0][0][0]);
  const _Float16* bbase = whTsw + (size_t)kh * 8 * 2048 + cp * 512 + c * 32 + ks * 8;

  float psA = 0.f, psB = 0.f;
  f32x4 acc = {0.f, 0.f, 0.f, 0.f};

  int4v sAa, sAb, sBa, sBb;          // depth-1 adj prefetch (16 VGPRs)
  float4 qa, qb;
  half8 b0, b1, b2, b3, b4, b5, b6, b7;

#define LOAD_ADJ(CH) do { \
    sAa = __builtin_nontemporal_load(reinterpret_cast<const int4v*>(adjA + (CH) * 512)); \
    sAb = __builtin_nontemporal_load(reinterpret_cast<const int4v*>(adjA + (CH) * 512 + 4)); \
    sBa = __builtin_nontemporal_load(reinterpret_cast<const int4v*>(adjB + (CH) * 512)); \
    sBb = __builtin_nontemporal_load(reinterpret_cast<const int4v*>(adjB + (CH) * 512 + 4)); \
  } while (0)

#define LOAD_WH(CH) do { \
    qa = *reinterpret_cast<const float4*>(wp + (CH) * 512); \
    qb = *reinterpret_cast<const float4*>(wp + (CH) * 512 + 4); \
  } while (0)

#define SC1(PS, PV, E, AV, QV, W1, MH) { \
    float x_ = (W1) + (QV); x_ = fmaxf(x_, LRALPHA * x_); \
    float p_ = ((AV) > 0) ? exp2f(x_ - (MH)) : 0.f; \
    (PS) += p_; (PV)[E] = (_Float16)p_; }

#define COMP_STORE(CH) do { \
    half8 pvA_, pvB_; \
    SC1(psA, pvA_, 0, sAa.x, qa.x, w1A, mhA) \
    SC1(psA, pvA_, 1, sAa.y, qa.y, w1A, mhA) \
    SC1(psA, pvA_, 2, sAa.z, qa.z, w1A, mhA) \
    SC1(psA, pvA_, 3, sAa.w, qa.w, w1A, mhA) \
    SC1(psA, pvA_, 4, sAb.x, qb.x, w1A, mhA) \
    SC1(psA, pvA_, 5, sAb.y, qb.y, w1A, mhA) \
    SC1(psA, pvA_, 6, sAb.z, qb.z, w1A, mhA) \
    SC1(psA, pvA_, 7, sAb.w, qb.w, w1A, mhA) \
    SC1(psB, pvB_, 0, sBa.x, qa.x, w1B, mhB) \
    SC1(psB, pvB_, 1, sBa.y, qa.y, w1B, mhB) \
    SC1(psB, pvB_, 2, sBa.z, qa.z, w1B, mhB) \
    SC1(psB, pvB_, 3, sBa.w, qa.w, w1B, mhB) \
    SC1(psB, pvB_, 4, sBb.x, qb.x, w1B, mhB) \
    SC1(psB, pvB_, 5, sBb.y, qb.y, w1B, mhB) \
    SC1(psB, pvB_, 6, sBb.z, qb.z, w1B, mhB) \
    SC1(psB, pvB_, 7, sBb.w, qb.w, w1B, mhB) \
    char* pb_ = PldsB + ((CH) & 1) * 16384; \
    *reinterpret_cast<half8*>(pb_ + rA * 1024 + ((lane * 16) ^ ((rA & 7) << 4))) = pvA_; \
    *reinterpret_cast<half8*>(pb_ + rB * 1024 + ((lane * 16) ^ ((rB & 7) << 4))) = pvB_; \
  } while (0)

#define PV_LOADB(CH) do { \
    const _Float16* bp_ = bbase + (size_t)(CH) * 32768; \
    b0 = *reinterpret_cast<const half8*>(bp_ + 0 * 2048); \
    b1 = *reinterpret_cast<const half8*>(bp_ + 1 * 2048); \
    b2 = *reinterpret_cast<const half8*>(bp_ + 2 * 2048); \
    b3 = *reinterpret_cast<const half8*>(bp_ + 3 * 2048); \
    b4 = *reinterpret_cast<const half8*>(bp_ + 4 * 2048); \
    b5 = *reinterpret_cast<const half8*>(bp_ + 5 * 2048); \
    b6 = *reinterpret_cast<const half8*>(bp_ + 6 * 2048); \
    b7 = *reinterpret_cast<const half8*>(bp_ + 7 * 2048); \
  } while (0)

#define PV_MFMA(CH) do { \
    const char* pr_ = PldsB + ((CH) & 1) * 16384 + c * 1024 + kh * 512; \
    half8 a_; \
    a_ = *reinterpret_cast<const half8*>(pr_ + ((0 * 64 + ks * 16) ^ cxor)); \
    acc = __builtin_amdgcn_mfma_f32_16x16x32_f16(a_, b0, acc, 0, 0, 0); \
    a_ = *reinterpret_cast<const half8*>(pr_ + ((1 * 64 + ks * 16) ^ cxor)); \
    acc = __builtin_amdgcn_mfma_f32_16x16x32_f16(a_, b1, acc, 0, 0, 0); \
    a_ = *reinterpret_cast<const half8*>(pr_ + ((2 * 64 + ks * 16) ^ cxor)); \
    acc = __builtin_amdgcn_mfma_f32_16x16x32_f16(a_, b2, acc, 0, 0, 0); \
    a_ = *reinterpret_cast<const half8*>(pr_ + ((3 * 64 + ks * 16) ^ cxor)); \
    acc = __builtin_amdgcn_mfma_f32_16x16x32_f16(a_, b3, acc, 0, 0, 0); \
    a_ = *reinterpret_cast<const half8*>(pr_ + ((4 * 64 + ks * 16) ^ cxor)); \
    acc = __builtin_amdgcn_mfma_f32_16x16x32_f16(a_, b4, acc, 0, 0, 0); \
    a_ = *reinterpret_cast<const half8*>(pr_ + ((5 * 64 + ks * 16) ^ cxor)); \
    acc = __builtin_amdgcn_mfma_f32_16x16x32_f16(a_, b5, acc, 0, 0, 0); \
    a_ = *reinterpret_cast<const half8*>(pr_ + ((6 * 64 + ks * 16) ^ cxor)); \
    acc = __builtin_amdgcn_mfma_f32_16x16x32_f16(a_, b6, acc, 0, 0, 0); \
    a_ = *reinterpret_cast<const half8*>(pr_ + ((7 * 64 + ks * 16) ^ cxor)); \
    acc = __builtin_amdgcn_mfma_f32_16x16x32_f16(a_, b7, acc, 0, 0, 0); \
  } while (0)

  // Per body CH: B-frags (L2) first so their vmcnt wait never drains the
  // younger adj loads; adj+wh for CH+1 in flight under PV_MFMA(CH); then
  // score+store for CH+1; barrier (drains everything anyway — depth-1 is
  // the correct prefetch depth under the barrier-drain regime).
#define BODY(CH) { \
    PV_LOADB(CH); \
    if ((CH) < 15) { LOAD_ADJ((CH) + 1); LOAD_WH((CH) + 1); } \
    PV_MFMA(CH); \
    if ((CH) < 15) COMP_STORE((CH) + 1); \
    __syncthreads(); }

  // prologue
  LOAD_ADJ(0);
  LOAD_WH(0);
  COMP_STORE(0);
  __syncthreads();

  BODY(0)  BODY(1)  BODY(2)  BODY(3)
  BODY(4)  BODY(5)  BODY(6)  BODY(7)
  BODY(8)  BODY(9)  BODY(10) BODY(11)
  BODY(12) BODY(13) BODY(14) BODY(15)

#undef BODY
#undef PV_MFMA
#undef PV_LOADB
#undef COMP_STORE
#undef SC1
#undef LOAD_WH
#undef LOAD_ADJ

  // ---- epilogue: denom reduce, split-K combine, divide, ELU, store ----
#pragma unroll
  for (int m = 1; m < 64; m <<= 1) {
    psA += __shfl_xor(psA, m);
    psB += __shfl_xor(psB, m);
  }
  if (lane == 0) { Dsh[rA] = psA; Dsh[rB] = psB; }
#pragma unroll
  for (int q = 0; q < 4; ++q) Osm[kh][cp][ks * 4 + q][c] = acc[q];
  __syncthreads();

  {
    const int row = t >> 5;
    const int col = (t & 31) * 2;
    const int cg = col >> 4, cc2 = col & 15;
    const float inv = 1.0f / Dsh[row];
    float o0 = (Osm[0][cg][row][cc2] + Osm[1][cg][row][cc2]) * inv;
    float o1 = (Osm[0][cg][row][cc2 + 1] + Osm[1][cg][row][cc2 + 1]) * inv;
    o0 = o0 > 0.f ? o0 : __expf(o0) - 1.f;
    o1 = o1 > 0.f ? o1 : __expf(o1) - 1.f;
    float2 o = {o0, o1};
    *reinterpret_cast<float2*>(&out[(size_t)(i0 + row) * 64 + col]) = o;
  }
}

// ---------------------------------------------------------------------------
extern "C" void kernel_launch(void* const* d_in, const int* in_sizes, int n_in,
                              void* d_out, int out_size, void* d_ws, size_t ws_size,
                              hipStream_t stream) {
  const float* h   = (const float*)d_in[0];
  const int*   adj = (const int*)d_in[1];
  const float* W   = (const float*)d_in[2];
  const float* a   = (const float*)d_in[3];
  float* out = (float*)d_out;

  char* ws = (char*)d_ws;
  _Float16* whTsw = (_Float16*)ws;                         // [0, 1MB)
  float* wh1s = (float*)(ws + 0x100000);                   // 32 KB
  float* wh2s = (float*)(ws + 0x108000);                   // 32 KB
  float* G    = (float*)(ws + 0x110000);                   // 4 B

  k1_wh<<<dim3(256), dim3(256), 0, stream>>>(h, W, a, whTsw, wh1s, wh2s);
  k1b_max<<<dim3(1), dim3(256), 0, stream>>>(wh2s, G);
  k2f<<<dim3(512), dim3(512), 0, stream>>>(adj, whTsw, wh1s, wh2s, G, out);
}